// Round 2
// baseline (502.314 us; speedup 1.0000x reference)
//
#include <hip/hip_runtime.h>
#include <math.h>

#define RES 128

// 4 lanes cooperate on one query. Each lane owns one (ox,oy) trilinear corner
// pair = 2 probes (oz=0/1) = 8 bilinear taps = 8x global_load_dwordx3.
// Rationale: the 1-thread/query version needed 96 live floats for full MLP but
// got only 68 VGPRs -> regalloc split the load batch AND occupancy fell to the
// 4-waves/SIMD tier. Splitting 4-ways keeps all loads in flight under ~48 VGPR
// -> 8 waves/SIMD tier, ~2x outstanding HBM lines per CU.
__global__ __launch_bounds__(256) void mel_kernel(
    const float* __restrict__ xyz, const float* __restrict__ l,
    const float* __restrict__ base, float* __restrict__ out, int n)
{
    int tid = blockIdx.x * blockDim.x + threadIdx.x;
    int q   = tid >> 2;   // query index
    int sub = tid & 3;    // (ox,oy) corner this lane owns
    if (q >= n) return;

    // ---- direction = l / max(||l||, 1e-9) ----
    float lx = l[3*q+0], ly = l[3*q+1], lz = l[3*q+2];
    float nrm = sqrtf(lx*lx + ly*ly + lz*lz);
    float inv = 1.0f / fmaxf(nrm, 1e-9f);
    float dx = lx*inv, dy = ly*inv, dz = lz*inv;

    // ---- cube face / uv (OpenGL convention) ----
    float ax = fabsf(dx), ay = fabsf(dy), az = fabsf(dz);
    bool is_x = (ax >= ay) && (ax >= az);
    bool is_y = (!is_x) && (ay >= az);

    int face;
    float ma, sc, tc;
    if (is_x) {
        face = (dx >= 0.0f) ? 0 : 1;
        ma = ax;
        sc = (dx >= 0.0f) ? -dz : dz;
        tc = -dy;
    } else if (is_y) {
        face = (dy >= 0.0f) ? 2 : 3;
        ma = ay;
        sc = dx;
        tc = (dy >= 0.0f) ? dz : -dz;
    } else {
        face = (dz >= 0.0f) ? 4 : 5;
        ma = az;
        sc = (dz >= 0.0f) ? dx : -dx;
        tc = -dy;
    }
    ma = fmaxf(ma, 1e-9f);
    float u = 0.5f * (sc / ma + 1.0f);
    float v = 0.5f * (tc / ma + 1.0f);

    // ---- bilinear tap coords on the 128x128 face ----
    float fx = u * (float)RES - 0.5f;
    float fy = v * (float)RES - 0.5f;
    float x0f = floorf(fx), y0f = floorf(fy);
    float tx = fx - x0f, ty = fy - y0f;
    int x0 = min(max((int)x0f,     0), RES-1);
    int x1 = min(max((int)x0f + 1, 0), RES-1);
    int y0 = min(max((int)y0f,     0), RES-1);
    int y1 = min(max((int)y0f + 1, 0), RES-1);

    // ---- trilinear probe corners on the (8,8,4) grid, span = 1 ----
    float px = xyz[3*q+0], py = xyz[3*q+1], pz = xyz[3*q+2];
    float cx = fminf(fmaxf(px * 7.0f, 0.0f), 7.0f);
    float cy = fminf(fmaxf(py * 7.0f, 0.0f), 7.0f);
    float cz = fminf(fmaxf(pz * 3.0f, 0.0f), 3.0f);
    int ix0 = (int)floorf(cx), iy0 = (int)floorf(cy), iz0 = (int)floorf(cz);
    int ix1 = min(ix0 + 1, 7), iy1 = min(iy0 + 1, 7), iz1 = min(iz0 + 1, 3);
    float tgx = cx - (float)ix0, tgy = cy - (float)iy0, tgz = cz - (float)iz0;

    // This lane's corner: ox = sub>>1, oy = sub&1; two probes differ in oz.
    int   ox  = sub >> 1, oy = sub & 1;
    float wxf = ox ? tgx : (1.0f - tgx);
    float wyf = oy ? tgy : (1.0f - tgy);
    int   gxi = ox ? ix1 : ix0;
    int   gyi = oy ? iy1 : iy0;
    float wxy = wxf * wyf;
    float pw0 = wxy * (1.0f - tgz);   // probe (gxi,gyi,iz0)
    float pw1 = wxy * tgz;            // probe (gxi,gyi,iz1)
    int   gb  = gxi*32 + gyi*4;
    int   p0  = gb + iz0;
    int   p1  = gb + iz1;

    // ---- bilinear weights / tap offsets (texel units within a face) ----
    int toff[4] = { y0*RES + x0, y0*RES + x1, y1*RES + x0, y1*RES + x1 };
    float bw[4];
    bw[0] = (1.0f - ty) * (1.0f - tx);
    bw[1] = (1.0f - ty) * tx;
    bw[2] = ty * (1.0f - tx);
    bw[3] = ty * tx;

    int face_off = face * (RES * RES);
    const float* bp0 = base + (size_t)(p0 * (6 * RES * RES) + face_off) * 3;
    const float* bp1 = base + (size_t)(p1 * (6 * RES * RES) + face_off) * 3;

    // ---- PHASE 1: issue all 8 gather loads (24 data VGPRs, all in flight) ----
    float v0[4][3], v1[4][3];
    #pragma unroll
    for (int t = 0; t < 4; ++t) {
        const float* a = bp0 + toff[t] * 3;
        v0[t][0] = a[0]; v0[t][1] = a[1]; v0[t][2] = a[2];
    }
    #pragma unroll
    for (int t = 0; t < 4; ++t) {
        const float* a = bp1 + toff[t] * 3;
        v1[t][0] = a[0]; v1[t][1] = a[1]; v1[t][2] = a[2];
    }

    // Keep the load batch intact: nothing may be scheduled across this point.
    __builtin_amdgcn_sched_barrier(0);

    // ---- PHASE 2: blend this lane's 2 probes ----
    float a0 = 0.0f, a1 = 0.0f, a2 = 0.0f;
    #pragma unroll
    for (int t = 0; t < 4; ++t) {
        float w0 = pw0 * bw[t];
        float w1 = pw1 * bw[t];
        a0 += w0 * v0[t][0] + w1 * v1[t][0];
        a1 += w0 * v0[t][1] + w1 * v1[t][1];
        a2 += w0 * v0[t][2] + w1 * v1[t][2];
    }
    float ws = pw0 + pw1;

    // ---- reduce across the 4-lane group (xor 1, then 2) ----
    a0 += __shfl_xor(a0, 1); a1 += __shfl_xor(a1, 1);
    a2 += __shfl_xor(a2, 1); ws += __shfl_xor(ws, 1);
    a0 += __shfl_xor(a0, 2); a1 += __shfl_xor(a1, 2);
    a2 += __shfl_xor(a2, 2); ws += __shfl_xor(ws, 2);

    if (sub == 0) {
        float winv = 1.0f / fmaxf(ws, 1e-8f);
        a0 *= winv; a1 *= winv; a2 *= winv;
        out[3*q+0] = 10.0f / (1.0f + __expf(-a0));
        out[3*q+1] = 10.0f / (1.0f + __expf(-a1));
        out[3*q+2] = 10.0f / (1.0f + __expf(-a2));
    }
}

extern "C" void kernel_launch(void* const* d_in, const int* in_sizes, int n_in,
                              void* d_out, int out_size, void* d_ws, size_t ws_size,
                              hipStream_t stream) {
    const float* xyz  = (const float*)d_in[0];
    const float* l    = (const float*)d_in[1];
    const float* base = (const float*)d_in[2];
    float* out = (float*)d_out;
    int n = in_sizes[0] / 3;                  // queries
    int blocks = (n + 63) / 64;               // 4 lanes/query, 64 queries/block
    mel_kernel<<<blocks, 256, 0, stream>>>(xyz, l, base, out, n);
}